// Round 2
// baseline (341.546 us; speedup 1.0000x reference)
//
#include <hip/hip_runtime.h>
#include <hip/hip_bf16.h>

#define N_NODES 100000
#define N_EDGES 1600000
#define NFEAT   128
#define NGRAPH  256
#define NACT    32
#define ECAP    64
#define OVF_CAP 8192

// ---- two-pass edge partition ----
#define BUCK_SHIFT 9
#define BUCK_NODES 512
#define NBUCK ((N_NODES + BUCK_NODES - 1) / BUCK_NODES)   // 196
#define SEGCAP 10240          // mean 8192, +22 sigma
#define CHUNK 4096            // edges per pass-1 block (R9-measured best)
#define NBLK1 ((N_EDGES + CHUNK - 1) / CHUNK)             // 391
#define BIN_NODES 128         // pass-2 nodes per block
#define NBLK2 ((N_NODES + BIN_NODES - 1) / BIN_NODES)     // 782
#define GB ((N_NODES + 63) / 64)                          // 1563 gemm blocks
#define WTBLK (2 * NFEAT * NFEAT / 256)                   // 128 wt blocks
#define LDSROW 136            // ushort row stride: 16B-aligned, uniform banks

typedef __attribute__((ext_vector_type(8))) short bf16x8;
typedef __attribute__((ext_vector_type(4))) float f32x4;

__device__ inline unsigned short f2bf(float f) {
  __hip_bfloat16 b = __float2bfloat16(f);
  return *reinterpret_cast<unsigned short*>(&b);
}
__device__ inline float2 bfu2f(unsigned u) {
  __hip_bfloat162 t = *reinterpret_cast<__hip_bfloat162*>(&u);
  return __bfloat1622float2(t);
}

// ---- launch 1: edgepart (blocks [0,NBLK1)) UNION wt transpose (rest) ----
__global__ __launch_bounds__(256) void edgepart_wt_kernel(const int* __restrict__ src,
                                                          const int* __restrict__ dst,
                                                          int* __restrict__ bucket_cursor,
                                                          int2* __restrict__ seg,
                                                          int* __restrict__ cnt,
                                                          int* __restrict__ ovf_cnt,
                                                          int* __restrict__ ovf,
                                                          const float* __restrict__ W1,
                                                          const float* __restrict__ W2,
                                                          unsigned short* __restrict__ Wt1,
                                                          unsigned short* __restrict__ Wt2) {
  __shared__ int2 stage[CHUNK];               // 32 KB
  __shared__ int hist[NBUCK], offs[NBUCK], cursor[NBUCK], gbase[NBUCK];
  __shared__ int sc[256];
  int tid = threadIdx.x;

  if (blockIdx.x >= NBLK1) {                  // ---- wt transpose part ----
    int i = (blockIdx.x - NBLK1) * 256 + tid; // 32768 weight elems
    int which = i >> 14;
    int idx = i & 16383;
    int n = idx >> 7, k = idx & 127;
    if (which == 0) Wt1[n * NFEAT + k] = f2bf(W1[k * NFEAT + n]);
    else            Wt2[n * NFEAT + k] = f2bf(W2[k * NFEAT + n]);
    return;
  }

  // ---- edgepart part ----
  int e0 = blockIdx.x * CHUNK;
  int m = N_EDGES - e0; if (m > CHUNK) m = CHUNK;

  for (int i = tid; i < NBUCK; i += 256) hist[i] = 0;
  __syncthreads();

  for (int i = tid; i < m; i += 256)
    atomicAdd(&hist[dst[e0 + i] >> BUCK_SHIFT], 1);
  __syncthreads();

  sc[tid] = (tid < NBUCK) ? hist[tid] : 0;
  __syncthreads();
  for (int ofs = 1; ofs < 256; ofs <<= 1) {
    int t = (tid >= ofs) ? sc[tid - ofs] : 0;
    __syncthreads();
    sc[tid] += t;
    __syncthreads();
  }
  if (tid < NBUCK) {
    int o = tid ? sc[tid - 1] : 0;
    offs[tid] = o;
    cursor[tid] = o;
    gbase[tid] = hist[tid] ? atomicAdd(&bucket_cursor[tid], hist[tid]) : 0;
  }
  __syncthreads();

  for (int i = tid; i < m; i += 256) {
    int2 p = make_int2(src[e0 + i], dst[e0 + i]);
    int pos = atomicAdd(&cursor[p.y >> BUCK_SHIFT], 1);
    stage[pos] = p;
  }
  __syncthreads();

  for (int i = tid; i < m; i += 256) {
    int2 p = stage[i];
    int bd = p.y >> BUCK_SHIFT;
    int gpos = gbase[bd] + (i - offs[bd]);
    if (gpos < SEGCAP) {
      seg[(size_t)bd * SEGCAP + gpos] = p;
    } else {                                // ~never: count + defer to agg ovf fixup
      atomicAdd(&cnt[p.y], 1);
      int o = atomicAdd(ovf_cnt, 1);
      if (o < OVF_CAP) { ovf[2 * o] = p.x; ovf[2 * o + 1] = p.y; }
    }
  }
}

// ---- launch 2: binbuild (blocks [0,NBLK2)) UNION layer-1 GEMM (rest) ----
__global__ __launch_bounds__(256) void binbuild_gemm_kernel(const int2* __restrict__ seg,
                                                            const int* __restrict__ bucket_cursor,
                                                            int* __restrict__ cnt,
                                                            float* __restrict__ dinv,
                                                            int* __restrict__ elist,
                                                            int* __restrict__ ovf_cnt,
                                                            int* __restrict__ ovf,
                                                            const float* __restrict__ x,
                                                            const unsigned short* __restrict__ Wt,
                                                            unsigned short* __restrict__ C) {
  __shared__ int lcnt[BIN_NODES];
  __shared__ int lel[BIN_NODES * ECAP];     // 32 KB
  int tid = threadIdx.x;

  if (blockIdx.x >= NBLK2) {                // ---- gemm1: C(bf16) = x(f32) @ W1 ----
    int bid = blockIdx.x - NBLK2;
    int wave = tid >> 6, lane = tid & 63;
    int q = lane >> 4, r = lane & 15;
    int m0 = bid * 64 + wave * 16;
    int arow = m0 + r; if (arow > N_NODES - 1) arow = N_NODES - 1;
    const float* Arow = x + (size_t)arow * NFEAT;

    f32x4 acc[8];
    #pragma unroll
    for (int t = 0; t < 8; ++t) acc[t] = (f32x4){0.f, 0.f, 0.f, 0.f};

    #pragma unroll
    for (int s = 0; s < 4; ++s) {
      int k0 = s * 32 + q * 8;
      float4 a0 = *(const float4*)(Arow + k0);
      float4 a1 = *(const float4*)(Arow + k0 + 4);
      bf16x8 xf;
      xf[0] = (short)f2bf(a0.x); xf[1] = (short)f2bf(a0.y);
      xf[2] = (short)f2bf(a0.z); xf[3] = (short)f2bf(a0.w);
      xf[4] = (short)f2bf(a1.x); xf[5] = (short)f2bf(a1.y);
      xf[6] = (short)f2bf(a1.z); xf[7] = (short)f2bf(a1.w);
      #pragma unroll
      for (int t = 0; t < 8; ++t) {
        bf16x8 wf = *(const bf16x8*)(Wt + (size_t)(t * 16 + r) * NFEAT + k0);
        acc[t] = __builtin_amdgcn_mfma_f32_16x16x32_bf16(wf, xf, acc[t], 0, 0, 0);
      }
    }
    int node = m0 + r;
    if (node < N_NODES) {
      uint2* Crow = (uint2*)(C + (size_t)node * NFEAT);
      #pragma unroll
      for (int t = 0; t < 8; ++t) {
        uint2 v;
        v.x = ((unsigned)f2bf(acc[t][1]) << 16) | f2bf(acc[t][0]);
        v.y = ((unsigned)f2bf(acc[t][3]) << 16) | f2bf(acc[t][2]);
        Crow[t * 4 + q] = v;    // features [t*16+q*4, +4)
      }
    }
    return;
  }

  // ---- binbuild part ----
  int n0 = blockIdx.x * BIN_NODES;
  int pb = n0 >> BUCK_SHIFT;
  if (tid < BIN_NODES) lcnt[tid] = 0;
  __syncthreads();
  int m = bucket_cursor[pb]; if (m > SEGCAP) m = SEGCAP;
  const int2* s = seg + (size_t)pb * SEGCAP;
  for (int e = tid; e < m; e += 256) {
    int2 p = s[e];
    unsigned ln = (unsigned)(p.y - n0);
    if (ln < (unsigned)BIN_NODES) {
      int pos = atomicAdd(&lcnt[ln], 1);
      if (pos < ECAP) {
        lel[(ln << 6) + pos] = p.x;
      } else {                              // high-degree node: agg ovf fixup
        int o = atomicAdd(ovf_cnt, 1);
        if (o < OVF_CAP) { ovf[2 * o] = p.x; ovf[2 * o + 1] = p.y; }
      }
    }
  }
  __syncthreads();
  if (tid < BIN_NODES) {
    int n = n0 + tid;
    if (n < N_NODES) {
      int tot = cnt[n] + lcnt[tid];          // cnt[n]: pass-1 ovf edges only
      cnt[n] = tot;                          // safe: block owns node range
      dinv[n] = rsqrtf((float)tot + 1.0f);   // fused dinv
    }
  }
  int4* gel = (int4*)(elist + (size_t)n0 * ECAP);
  const int4* lel4 = (const int4*)lel;
  for (int i = tid; i < BIN_NODES * ECAP / 4; i += 256) gel[i] = lel4[i];
}

// ---------------- launch 3: layer-1 aggregation FUSED with layer-2 GEMM ------
// R1 restructure: FULL WAVE per node (512 thr = 8 waves = 8 nodes/block).
// Each lane loads uint4 (16B): 16 lanes cover a 256B h-row, 4 rows per load
// instruction, so one 8-reg chunk puts 32 edges in flight -> ~1 serialized
// memory-latency exposure per wave (vs ~3 with the half-wave 8-edge scheme).
// Lane (rg=lane>>4, l16=lane&15) accumulates features [l16*8,+8) of edges in
// row-group rg; an xor-16/xor-32 butterfly combines the 4 row-groups at the
// end. Self + ovf terms are gated to rg==0 so they are counted exactly once.
__global__ __launch_bounds__(512) void agg_gemm_kernel(const uint2* __restrict__ h2,
                                                       const int* __restrict__ elist,
                                                       const int* __restrict__ cnt,
                                                       const float* __restrict__ dinv,
                                                       const float* __restrict__ bias,
                                                       const int* __restrict__ ovf_cnt,
                                                       const int* __restrict__ ovf,
                                                       const unsigned short* __restrict__ Wt2,
                                                       unsigned short* __restrict__ H2) {
  __shared__ __align__(16) unsigned short hloc[16 * LDSROW];  // rows 8-15 unused pad
  int tid = threadIdx.x;
  int lane = tid & 63;
  int lw = tid >> 6;                         // local wave = local node 0..7
  int l16 = lane & 15;                       // feature block [l16*8, +8)
  int rg = lane >> 4;                        // row group 0..3
  int l32 = lane & 31;
  int n0 = blockIdx.x * 8;
  int n = n0 + lw;                           // grid exact: 12500*8 == N_NODES

  float dn = dinv[n];
  int c = cnt[n]; c = (c > ECAP) ? ECAP : c;
  const int* el = elist + (size_t)n * ECAP;

  int   s0 = (l32 < c)      ? el[l32]      : n;
  float w0 = (l32 < c)      ? dinv[s0] * dn : 0.f;
  int   s1 = (l32 + 32 < c) ? el[l32 + 32] : n;
  float w1 = (l32 + 32 < c) ? dinv[s1] * dn : 0.f;

  const uint4* h4 = (const uint4*)h2;
  uint4 hv = h4[(size_t)n * 16 + l16];       // self row (1 coalesced 256B/wave)
  float sw = (rg == 0) ? dn * dn : 0.f;      // count self exactly once
  float acc[8];
  {
    float2 f0 = bfu2f(hv.x), f1 = bfu2f(hv.y), f2 = bfu2f(hv.z), f3 = bfu2f(hv.w);
    acc[0] = sw * f0.x; acc[1] = sw * f0.y; acc[2] = sw * f1.x; acc[3] = sw * f1.y;
    acc[4] = sw * f2.x; acc[5] = sw * f2.y; acc[6] = sw * f3.x; acc[7] = sw * f3.y;
  }

  // ---- chunk 0: edges [0,32) in flight ----
  uint4 pv[8];
  #pragma unroll
  for (int r = 0; r < 8; ++r) pv[r] = hv;    // pad default (w=0 below)
  #pragma unroll
  for (int r = 0; r < 8; ++r) {
    if (r * 4 < c) {                         // wave-uniform guard
      int s = __shfl(s0, r * 4 + rg, 32);
      pv[r] = h4[(size_t)s * 16 + l16];
    }
  }
  #pragma unroll
  for (int r = 0; r < 8; ++r) {
    if (r * 4 < c) {
      float w = __shfl(w0, r * 4 + rg, 32);
      float2 f0 = bfu2f(pv[r].x), f1 = bfu2f(pv[r].y);
      float2 f2 = bfu2f(pv[r].z), f3 = bfu2f(pv[r].w);
      acc[0] = fmaf(w, f0.x, acc[0]); acc[1] = fmaf(w, f0.y, acc[1]);
      acc[2] = fmaf(w, f1.x, acc[2]); acc[3] = fmaf(w, f1.y, acc[3]);
      acc[4] = fmaf(w, f2.x, acc[4]); acc[5] = fmaf(w, f2.y, acc[5]);
      acc[6] = fmaf(w, f3.x, acc[6]); acc[7] = fmaf(w, f3.y, acc[7]);
    }
  }
  // ---- chunk 1: edges [32,64) (P(c>32) ~ 1e-4, wave-uniform branch) ----
  if (c > 32) {
    #pragma unroll
    for (int r = 0; r < 8; ++r) {
      if (32 + r * 4 < c) {
        int s = __shfl(s1, r * 4 + rg, 32);
        pv[r] = h4[(size_t)s * 16 + l16];
      }
    }
    #pragma unroll
    for (int r = 0; r < 8; ++r) {
      if (32 + r * 4 < c) {
        float w = __shfl(w1, r * 4 + rg, 32);
        float2 f0 = bfu2f(pv[r].x), f1 = bfu2f(pv[r].y);
        float2 f2 = bfu2f(pv[r].z), f3 = bfu2f(pv[r].w);
        acc[0] = fmaf(w, f0.x, acc[0]); acc[1] = fmaf(w, f0.y, acc[1]);
        acc[2] = fmaf(w, f1.x, acc[2]); acc[3] = fmaf(w, f1.y, acc[3]);
        acc[4] = fmaf(w, f2.x, acc[4]); acc[5] = fmaf(w, f2.y, acc[5]);
        acc[6] = fmaf(w, f3.x, acc[6]); acc[7] = fmaf(w, f3.y, acc[7]);
      }
    }
  }

  int m = *ovf_cnt; if (m > OVF_CAP) m = OVF_CAP;
  for (int p = 0; p < m; ++p) {
    int s = ovf[2 * p], d = ovf[2 * p + 1];
    if (d == n) {
      float w = (rg == 0) ? dinv[s] * dn : 0.f;   // count once
      uint4 pvv = h4[(size_t)s * 16 + l16];
      float2 f0 = bfu2f(pvv.x), f1 = bfu2f(pvv.y);
      float2 f2 = bfu2f(pvv.z), f3 = bfu2f(pvv.w);
      acc[0] = fmaf(w, f0.x, acc[0]); acc[1] = fmaf(w, f0.y, acc[1]);
      acc[2] = fmaf(w, f1.x, acc[2]); acc[3] = fmaf(w, f1.y, acc[3]);
      acc[4] = fmaf(w, f2.x, acc[4]); acc[5] = fmaf(w, f2.y, acc[5]);
      acc[6] = fmaf(w, f3.x, acc[6]); acc[7] = fmaf(w, f3.y, acc[7]);
    }
  }

  // combine the 4 row-groups (all lanes end with the full sum for their l16)
  #pragma unroll
  for (int k = 0; k < 8; ++k) {
    acc[k] += __shfl_xor(acc[k], 16);
    acc[k] += __shfl_xor(acc[k], 32);
  }

  if (rg == 0) {                             // 16 lanes write the node row
    float4 b0 = ((const float4*)bias)[l16 * 2];
    float4 b1 = ((const float4*)bias)[l16 * 2 + 1];
    uint4 v;
    v.x = ((unsigned)f2bf(fmaxf(acc[1] + b0.y, 0.f)) << 16) | f2bf(fmaxf(acc[0] + b0.x, 0.f));
    v.y = ((unsigned)f2bf(fmaxf(acc[3] + b0.w, 0.f)) << 16) | f2bf(fmaxf(acc[2] + b0.z, 0.f));
    v.z = ((unsigned)f2bf(fmaxf(acc[5] + b1.y, 0.f)) << 16) | f2bf(fmaxf(acc[4] + b1.x, 0.f));
    v.w = ((unsigned)f2bf(fmaxf(acc[7] + b1.w, 0.f)) << 16) | f2bf(fmaxf(acc[6] + b1.z, 0.f));
    *(uint4*)(&hloc[lw * LDSROW + l16 * 8]) = v;
  }
  __syncthreads();

  // ---- phase 2: gemm2 tile. wave lw -> output feats [lw*16, lw*16+16) ----
  // 16-row MFMA tile; rows 8-15 are stale LDS -> garbage only in D columns
  // 8-15 (per-node-independent), which are never stored.
  int q = lane >> 4, r = lane & 15;
  f32x4 acc2 = (f32x4){0.f, 0.f, 0.f, 0.f};
  #pragma unroll
  for (int s = 0; s < 4; ++s) {
    int k0 = s * 32 + q * 8;
    bf16x8 xf = *(const bf16x8*)(&hloc[r * LDSROW + k0]);
    bf16x8 wf = *(const bf16x8*)(Wt2 + (size_t)(lw * 16 + r) * NFEAT + k0);
    acc2 = __builtin_amdgcn_mfma_f32_16x16x32_bf16(wf, xf, acc2, 0, 0, 0);
  }
  if (r < 8) {
    int node = n0 + r;
    uint2* Crow = (uint2*)(H2 + (size_t)node * NFEAT);
    uint2 o;
    o.x = ((unsigned)f2bf(acc2[1]) << 16) | f2bf(acc2[0]);
    o.y = ((unsigned)f2bf(acc2[3]) << 16) | f2bf(acc2[2]);
    Crow[lw * 4 + q] = o;                    // feats [lw*16+q*4, +4)
  }
}

// ---------------- launch 4: layer-2 aggregation + FUSED POOL ----------------
// Same full-wave-per-node gather as agg_gemm (512 thr = 8 waves = 8 nodes).
__global__ __launch_bounds__(512) void agg_pool_kernel(const uint2* __restrict__ h2,
                                                       const int* __restrict__ elist,
                                                       const int* __restrict__ cnt,
                                                       const float* __restrict__ dinv,
                                                       const float* __restrict__ bias,
                                                       const int* __restrict__ ovf_cnt,
                                                       const int* __restrict__ ovf,
                                                       const int* __restrict__ batch,
                                                       float* __restrict__ gsum) {
  __shared__ float lds[8][NFEAT];            // 4 KB
  int tid = threadIdx.x;
  int lane = tid & 63;
  int lw = tid >> 6;
  int l16 = lane & 15;
  int rg = lane >> 4;
  int l32 = lane & 31;
  int n0 = blockIdx.x * 8;
  int n = n0 + lw;                           // grid exact: 12500*8 == N_NODES

  float dn = dinv[n];
  int c = cnt[n]; c = (c > ECAP) ? ECAP : c;
  const int* el = elist + (size_t)n * ECAP;

  int   s0 = (l32 < c)      ? el[l32]      : n;
  float w0 = (l32 < c)      ? dinv[s0] * dn : 0.f;
  int   s1 = (l32 + 32 < c) ? el[l32 + 32] : n;
  float w1 = (l32 + 32 < c) ? dinv[s1] * dn : 0.f;

  const uint4* h4 = (const uint4*)h2;
  uint4 hv = h4[(size_t)n * 16 + l16];
  float sw = (rg == 0) ? dn * dn : 0.f;
  float acc[8];
  {
    float2 f0 = bfu2f(hv.x), f1 = bfu2f(hv.y), f2 = bfu2f(hv.z), f3 = bfu2f(hv.w);
    acc[0] = sw * f0.x; acc[1] = sw * f0.y; acc[2] = sw * f1.x; acc[3] = sw * f1.y;
    acc[4] = sw * f2.x; acc[5] = sw * f2.y; acc[6] = sw * f3.x; acc[7] = sw * f3.y;
  }

  uint4 pv[8];
  #pragma unroll
  for (int r = 0; r < 8; ++r) pv[r] = hv;
  #pragma unroll
  for (int r = 0; r < 8; ++r) {
    if (r * 4 < c) {
      int s = __shfl(s0, r * 4 + rg, 32);
      pv[r] = h4[(size_t)s * 16 + l16];
    }
  }
  #pragma unroll
  for (int r = 0; r < 8; ++r) {
    if (r * 4 < c) {
      float w = __shfl(w0, r * 4 + rg, 32);
      float2 f0 = bfu2f(pv[r].x), f1 = bfu2f(pv[r].y);
      float2 f2 = bfu2f(pv[r].z), f3 = bfu2f(pv[r].w);
      acc[0] = fmaf(w, f0.x, acc[0]); acc[1] = fmaf(w, f0.y, acc[1]);
      acc[2] = fmaf(w, f1.x, acc[2]); acc[3] = fmaf(w, f1.y, acc[3]);
      acc[4] = fmaf(w, f2.x, acc[4]); acc[5] = fmaf(w, f2.y, acc[5]);
      acc[6] = fmaf(w, f3.x, acc[6]); acc[7] = fmaf(w, f3.y, acc[7]);
    }
  }
  if (c > 32) {
    #pragma unroll
    for (int r = 0; r < 8; ++r) {
      if (32 + r * 4 < c) {
        int s = __shfl(s1, r * 4 + rg, 32);
        pv[r] = h4[(size_t)s * 16 + l16];
      }
    }
    #pragma unroll
    for (int r = 0; r < 8; ++r) {
      if (32 + r * 4 < c) {
        float w = __shfl(w1, r * 4 + rg, 32);
        float2 f0 = bfu2f(pv[r].x), f1 = bfu2f(pv[r].y);
        float2 f2 = bfu2f(pv[r].z), f3 = bfu2f(pv[r].w);
        acc[0] = fmaf(w, f0.x, acc[0]); acc[1] = fmaf(w, f0.y, acc[1]);
        acc[2] = fmaf(w, f1.x, acc[2]); acc[3] = fmaf(w, f1.y, acc[3]);
        acc[4] = fmaf(w, f2.x, acc[4]); acc[5] = fmaf(w, f2.y, acc[5]);
        acc[6] = fmaf(w, f3.x, acc[6]); acc[7] = fmaf(w, f3.y, acc[7]);
      }
    }
  }

  int m = *ovf_cnt; if (m > OVF_CAP) m = OVF_CAP;
  for (int p = 0; p < m; ++p) {
    int s = ovf[2 * p], d = ovf[2 * p + 1];
    if (d == n) {
      float w = (rg == 0) ? dinv[s] * dn : 0.f;
      uint4 pvv = h4[(size_t)s * 16 + l16];
      float2 f0 = bfu2f(pvv.x), f1 = bfu2f(pvv.y);
      float2 f2 = bfu2f(pvv.z), f3 = bfu2f(pvv.w);
      acc[0] = fmaf(w, f0.x, acc[0]); acc[1] = fmaf(w, f0.y, acc[1]);
      acc[2] = fmaf(w, f1.x, acc[2]); acc[3] = fmaf(w, f1.y, acc[3]);
      acc[4] = fmaf(w, f2.x, acc[4]); acc[5] = fmaf(w, f2.y, acc[5]);
      acc[6] = fmaf(w, f3.x, acc[6]); acc[7] = fmaf(w, f3.y, acc[7]);
    }
  }

  #pragma unroll
  for (int k = 0; k < 8; ++k) {
    acc[k] += __shfl_xor(acc[k], 16);
    acc[k] += __shfl_xor(acc[k], 32);
  }

  if (rg == 0) {
    float4 b0 = ((const float4*)bias)[l16 * 2];
    float4 b1 = ((const float4*)bias)[l16 * 2 + 1];
    float4 v0, v1;
    v0.x = fmaxf(acc[0] + b0.x, 0.f); v0.y = fmaxf(acc[1] + b0.y, 0.f);
    v0.z = fmaxf(acc[2] + b0.z, 0.f); v0.w = fmaxf(acc[3] + b0.w, 0.f);
    v1.x = fmaxf(acc[4] + b1.x, 0.f); v1.y = fmaxf(acc[5] + b1.y, 0.f);
    v1.z = fmaxf(acc[6] + b1.z, 0.f); v1.w = fmaxf(acc[7] + b1.w, 0.f);
    *(float4*)(&lds[lw][l16 * 8]) = v0;
    *(float4*)(&lds[lw][l16 * 8 + 4]) = v1;
  }
  __syncthreads();

  if (tid < NFEAT) {                         // thread t = feature t
    float sum = 0.f;
    int cur = batch[n0];
    #pragma unroll
    for (int i = 0; i < 8; ++i) {
      int b = batch[n0 + i];
      if (b != cur) {
        atomicAdd(&gsum[cur * NFEAT + tid], sum);
        sum = 0.f; cur = b;
      }
      sum += lds[i][tid];
    }
    atomicAdd(&gsum[cur * NFEAT + tid], sum);
  }
}

// ---------------- MLP head (graph-count binary search fused in) ----------------
__global__ __launch_bounds__(128) void mlp_kernel(const float* __restrict__ gsum,
                                                  const int* __restrict__ batch,
                                                  const float* __restrict__ Wl1,
                                                  const float* __restrict__ bl1,
                                                  const float* __restrict__ Wl2,
                                                  const float* __restrict__ bl2,
                                                  float* __restrict__ out) {
  __shared__ float gr[NFEAT];
  __shared__ float t1[NFEAT];
  __shared__ float sinv;
  int g = blockIdx.x, t = threadIdx.x;
  if (t == 0) {
    int lo = 0, hi = N_NODES;
    while (lo < hi) { int mid = (lo + hi) >> 1; if (batch[mid] < g) lo = mid + 1; else hi = mid; }
    int lo2 = lo, hi2 = N_NODES;
    while (lo2 < hi2) { int mid = (lo2 + hi2) >> 1; if (batch[mid] < g + 1) lo2 = mid + 1; else hi2 = mid; }
    sinv = 1.0f / fmaxf((float)(lo2 - lo), 1.0f);
  }
  __syncthreads();
  gr[t] = gsum[g * NFEAT + t] * sinv;
  __syncthreads();
  float acc = bl1[t];
  for (int k = 0; k < NFEAT; ++k) acc = fmaf(gr[k], Wl1[k * NFEAT + t], acc);
  t1[t] = fmaxf(acc, 0.f);
  __syncthreads();
  if (t < NACT) {
    float a2 = bl2[t];
    for (int k = 0; k < NFEAT; ++k) a2 = fmaf(t1[k], Wl2[k * NACT + t], a2);
    out[g * NACT + t] = a2;
  }
}

extern "C" void kernel_launch(void* const* d_in, const int* in_sizes, int n_in,
                              void* d_out, int out_size, void* d_ws, size_t ws_size,
                              hipStream_t stream) {
  const float* x    = (const float*)d_in[0];
  const int*   ei   = (const int*)d_in[1];
  const int*   batch= (const int*)d_in[2];
  const float* W1   = (const float*)d_in[3];
  const float* b1   = (const float*)d_in[4];
  const float* W2   = (const float*)d_in[5];
  const float* b2   = (const float*)d_in[6];
  const float* Wl1  = (const float*)d_in[7];
  const float* bl1  = (const float*)d_in[8];
  const float* Wl2  = (const float*)d_in[9];
  const float* bl2  = (const float*)d_in[10];
  float* out = (float*)d_out;

  const int* srcp = ei;            // edge_index[0]
  const int* dstp = ei + N_EDGES;  // edge_index[1]

  char* base = (char*)d_ws;
  size_t off = 0;
  auto alloc = [&](size_t bytes) -> void* {
    void* p = base + off;
    off += (bytes + 511) & ~(size_t)511;
    return p;
  };
  int*   cnt     = (int*)alloc((size_t)N_NODES * 4);
  int*   ovfc    = (int*)alloc(4);
  float* gsum    = (float*)alloc((size_t)NGRAPH * NFEAT * 4);
  int*   bucket_cursor = (int*)alloc((size_t)NBUCK * 4);
  size_t zspan   = off;  // everything above must start zeroed
  float* dinv    = (float*)alloc((size_t)N_NODES * 4);
  int*   elist   = (int*)alloc((size_t)NBLK2 * BIN_NODES * ECAP * 4); // padded
  int*   ovf     = (int*)alloc((size_t)OVF_CAP * 2 * 4);
  int2*  seg     = (int2*)alloc((size_t)NBUCK * SEGCAP * 8);          // 16 MB
  unsigned short* Wt1 = (unsigned short*)alloc((size_t)NFEAT * NFEAT * 2);
  unsigned short* Wt2 = (unsigned short*)alloc((size_t)NFEAT * NFEAT * 2);
  unsigned short* H1 = (unsigned short*)alloc((size_t)N_NODES * NFEAT * 2); // bf16
  unsigned short* H2 = (unsigned short*)alloc((size_t)N_NODES * NFEAT * 2); // bf16

  hipMemsetAsync(d_ws, 0, zspan, stream);

  const int FB = N_NODES / 8;             // 12500 blocks, 8 nodes each (full-wave gather)

  // L1: edge partition UNION weight transpose (independent)
  edgepart_wt_kernel<<<NBLK1 + WTBLK, 256, 0, stream>>>(
      srcp, dstp, bucket_cursor, seg, cnt, ovfc, ovf, W1, W2, Wt1, Wt2);
  // L2: elist build UNION layer-1 GEMM (independent; both dep on L1)
  binbuild_gemm_kernel<<<NBLK2 + GB, 256, 0, stream>>>(
      seg, bucket_cursor, cnt, dinv, elist, ovfc, ovf, x, Wt1, H1);
  // L3: layer-1 aggregation FUSED with layer-2 GEMM (no intermediate buffer)
  agg_gemm_kernel<<<FB, 512, 0, stream>>>((const uint2*)H1, elist, cnt, dinv, b1,
                                          ovfc, ovf, Wt2, H2);
  // L4: layer-2 aggregation + fused pool
  agg_pool_kernel<<<FB, 512, 0, stream>>>((const uint2*)H2, elist, cnt, dinv, b2,
                                          ovfc, ovf, batch, gsum);
  // L5: head
  mlp_kernel<<<NGRAPH, 128, 0, stream>>>(gsum, batch, Wl1, bl1, Wl2, bl2, out);
}